// Round 5
// baseline (336.471 us; speedup 1.0000x reference)
//
#include <hip/hip_runtime.h>
#include <math.h>

#define N_NODES 100000
#define N_FEAT  256
#define K_SEL   50000
#define N_EDGES 3200000
#define NBUCKET 65536
#define NCHUNK  256                         /* NBUCKET / 256 bins per chunk */

#define GATHER_BLOCKS (K_SEL / 4)           /* 4 rows (64 lanes ea) per 256-thr block */
#define EDGE_BLOCKS   (N_EDGES / (4 * 256)) /* 4 edges per thread */

typedef float __attribute__((ext_vector_type(4))) floatx4;
typedef int   __attribute__((ext_vector_type(4))) intx4;

// ---- key encodings -------------------------------------------------------
// ascending uint64 key == descending z, so stable-ascending == top_k order
__device__ __forceinline__ unsigned long long descKey(double z) {
    unsigned long long u = (unsigned long long)__double_as_longlong(z);
    unsigned long long a = (u >> 63) ? ~u : (u | 0x8000000000000000ULL);
    return ~a;
}

// exact inverse of descKey (bit-exact roundtrip, finite values)
__device__ __forceinline__ double invKey(unsigned long long k) {
    unsigned long long a = ~k;
    unsigned long long u = (a >> 63) ? (a & 0x7FFFFFFFFFFFFFFFULL) : ~a;
    return __longlong_as_double((long long)u);
}

__device__ __forceinline__ unsigned int bucketOfFloat(float zf) {
    unsigned int u = __float_as_uint(zf);
    unsigned int a = (u >> 31) ? ~u : (u | 0x80000000u);
    return (~a) >> 16;
}

__device__ __forceinline__ double dot4d(float4 a, float4 b) {
    return (double)a.x * (double)b.x + (double)a.y * (double)b.y +
           (double)a.z * (double)b.z + (double)a.w * (double)b.w;
}

// ---- kernels -------------------------------------------------------------
// score: THREAD-per-row GEMV. One thread owns one full 256-float row:
// 64 float4 loads (each lane's 4 consecutive loads = one 64B line -> L1
// absorbs reuse), fp64 accumulate in 4 interleaved accumulators
// (deterministic order), ZERO cross-lane ops. Wave count collapses
// 25000 -> 1563 (64-thr blocks for CU balance). w staged in LDS once per
// block; ds_read broadcast (same-address) is conflict-free.
__global__ void __launch_bounds__(64) score_kernel(
        const float* __restrict__ x, const float* __restrict__ w,
        unsigned long long* __restrict__ key64, int* __restrict__ hist) {
    __shared__ float4 ws[64];
    const int t = threadIdx.x;
    ws[t] = ((const float4*)w)[t];
    __syncthreads();
    const int row = blockIdx.x * 64 + t;
    if (row >= N_NODES) return;
    const float4* xr = (const float4*)(x + (size_t)row * N_FEAT);
    double a0 = 0.0, a1 = 0.0, a2 = 0.0, a3 = 0.0;
#pragma unroll
    for (int jj = 0; jj < 8; ++jj) {
        const int base = jj * 8;
        float4 v0 = xr[base + 0], v1 = xr[base + 1];
        float4 v2 = xr[base + 2], v3 = xr[base + 3];
        float4 v4 = xr[base + 4], v5 = xr[base + 5];
        float4 v6 = xr[base + 6], v7 = xr[base + 7];
        a0 += dot4d(v0, ws[base + 0]);
        a1 += dot4d(v1, ws[base + 1]);
        a2 += dot4d(v2, ws[base + 2]);
        a3 += dot4d(v3, ws[base + 3]);
        a0 += dot4d(v4, ws[base + 4]);
        a1 += dot4d(v5, ws[base + 5]);
        a2 += dot4d(v6, ws[base + 6]);
        a3 += dot4d(v7, ws[base + 7]);
    }
    double acc = (a0 + a1) + (a2 + a3);
    key64[row] = descKey(acc);
    atomicAdd(&hist[bucketOfFloat((float)acc)], 1);
}

// chunked scan: block c scans its 256 bins into chunk-LOCAL exclusive
// prefixes (-> start[]); last-arriving block scans the 256 chunk totals into
// chunkOff[]. Block 0 additionally computes ||w|| in fp64.
__global__ void __launch_bounds__(256) scan_kernel(const int* __restrict__ hist,
                                                   const float* __restrict__ w,
                                                   double* __restrict__ normp,
                                                   int* __restrict__ start,
                                                   int* __restrict__ chunkSums,
                                                   int* __restrict__ chunkOff,
                                                   int* __restrict__ counter) {
    __shared__ int s[256];
    __shared__ double sd[256];
    __shared__ int lastFlag;
    int c = blockIdx.x, t = threadIdx.x;
    if (c == 0) {                       /* ||w|| reduction, fp64 */
        double v = (double)w[t];
        sd[t] = v * v;
        __syncthreads();
        for (int off = 128; off > 0; off >>= 1) {
            if (t < off) sd[t] += sd[t + off];
            __syncthreads();
        }
        if (t == 0) normp[0] = sqrt(sd[0]);
    }
    int v = hist[c * 256 + t];
    s[t] = v;
    __syncthreads();
    for (int off = 1; off < 256; off <<= 1) {
        int add = (t >= off) ? s[t - off] : 0;
        __syncthreads();
        s[t] += add;
        __syncthreads();
    }
    start[c * 256 + t] = s[t] - v; /* chunk-local exclusive prefix */
    if (t == 0) {
        atomicExch(&chunkSums[c], s[255]);   /* device-scope publish */
        __threadfence();
        int old = atomicAdd(counter, 1);
        lastFlag = (old == NCHUNK - 1);
    }
    __syncthreads();
    if (!lastFlag) return;
    int wsum = atomicAdd(&chunkSums[t], 0);  /* device-coherent read */
    __syncthreads();
    s[t] = wsum;
    __syncthreads();
    for (int off = 1; off < 256; off <<= 1) {
        int add = (t >= off) ? s[t - off] : 0;
        __syncthreads();
        s[t] += add;
        __syncthreads();
    }
    chunkOff[t] = s[t] - wsum; /* global exclusive offset of chunk t */
}

// scatter nodes to their bucket's slot range; consumes start[] via atomicAdd
__global__ void scatter_kernel(const unsigned long long* __restrict__ key64,
                               int* __restrict__ start,
                               const int* __restrict__ chunkOff,
                               unsigned long long* __restrict__ slotKey,
                               int* __restrict__ slotIdx) {
    int i = blockIdx.x * blockDim.x + threadIdx.x;
    if (i >= N_NODES) return;
    unsigned long long k = key64[i];
    int b = (int)bucketOfFloat((float)invKey(k));
    int pos = atomicAdd(&start[b], 1) + chunkOff[b >> 8];
    slotKey[pos] = k;
    slotIdx[pos] = i;
}

// exact rank within bucket via fp64 key + index tie-break.
// post-scatter start[b]+chunkOff == bucket end; begin = end - hist[b].
// buckets entirely below the cutoff (st >= K) short-circuit to mapping=-1.
__global__ void rank_kernel(const unsigned long long* __restrict__ slotKey,
                            const int* __restrict__ slotIdx,
                            const int* __restrict__ start, const int* __restrict__ hist,
                            const int* __restrict__ chunkOff,
                            float* __restrict__ mappingF, int* __restrict__ perm,
                            float* __restrict__ selDot) {
    int s = blockIdx.x * blockDim.x + threadIdx.x;
    if (s >= N_NODES) return;
    unsigned long long myKey = slotKey[s];
    int i = slotIdx[s];
    float df = (float)invKey(myKey);
    int b = (int)bucketOfFloat(df);
    int end = start[b] + chunkOff[b >> 8];
    int cnt = hist[b];
    int st = end - cnt;
    if (st >= K_SEL) {                        /* whole bucket below cutoff */
        mappingF[i] = -1.0f;
        return;
    }
    int rank = 0;
    if (cnt > 1) {
        for (int q = st; q < end; ++q) {
            unsigned long long k = slotKey[q];
            if (k < myKey || (k == myKey && slotIdx[q] < i)) ++rank;
        }
    }
    int p = st + rank;
    if (p < K_SEL) {
        mappingF[i] = (float)p;
        perm[p] = i;
        selDot[p] = df;
    } else {
        mappingF[i] = -1.0f;
    }
}

// fused output: blocks [0,GATHER_BLOCKS) gather+gate x rows (tanh here, fp32,
// selected rows only); blocks [GATHER_BLOCKS,...) remap edges, 4/thread int4
__global__ void out_kernel(const float* __restrict__ x, const int* __restrict__ perm,
                           const float* __restrict__ selDot,
                           const double* __restrict__ normp,
                           const int* __restrict__ ei,
                           const float* __restrict__ mappingF,
                           float* __restrict__ out) {
    if (blockIdx.x < GATHER_BLOCKS) {
        int tid = blockIdx.x * 256 + threadIdx.x;
        int r = tid >> 6;
        int c = (tid & 63) << 2;
        int src = perm[r];
        float sc = tanhf(selDot[r] / (float)normp[0]);
        float4 v = *(const float4*)(x + (size_t)src * N_FEAT + c);
        floatx4 o;
        o.x = v.x * sc; o.y = v.y * sc; o.z = v.z * sc; o.w = v.w * sc;
        __builtin_nontemporal_store(o, (floatx4*)(out + (size_t)r * N_FEAT + c));
    } else {
        int tid = (blockIdx.x - GATHER_BLOCKS) * 256 + threadIdx.x;
        int e = tid << 2;
        intx4 a = __builtin_nontemporal_load((const intx4*)(ei + e));
        intx4 b = __builtin_nontemporal_load((const intx4*)(ei + N_EDGES + e));
        float* oeu = out + (size_t)K_SEL * N_FEAT;
        float* oev = oeu + N_EDGES;
        float m0 = mappingF[a.x], m1 = mappingF[a.y];
        float m2 = mappingF[a.z], m3 = mappingF[a.w];
        float n0 = mappingF[b.x], n1 = mappingF[b.y];
        float n2 = mappingF[b.z], n3 = mappingF[b.w];
        floatx4 ou, ov;
        bool v0 = (m0 >= 0.0f) && (n0 >= 0.0f);
        bool v1 = (m1 >= 0.0f) && (n1 >= 0.0f);
        bool v2 = (m2 >= 0.0f) && (n2 >= 0.0f);
        bool v3 = (m3 >= 0.0f) && (n3 >= 0.0f);
        ou.x = v0 ? m0 : -1.0f; ov.x = v0 ? n0 : -1.0f;
        ou.y = v1 ? m1 : -1.0f; ov.y = v1 ? n1 : -1.0f;
        ou.z = v2 ? m2 : -1.0f; ov.z = v2 ? n2 : -1.0f;
        ou.w = v3 ? m3 : -1.0f; ov.w = v3 ? n3 : -1.0f;
        __builtin_nontemporal_store(ou, (floatx4*)(oeu + e));
        __builtin_nontemporal_store(ov, (floatx4*)(oev + e));
    }
}

// ---- launch --------------------------------------------------------------
extern "C" void kernel_launch(void* const* d_in, const int* in_sizes, int n_in,
                              void* d_out, int out_size, void* d_ws, size_t ws_size,
                              hipStream_t stream) {
    const float* x  = (const float*)d_in[0];
    const int*   ei = (const int*)d_in[1];
    const float* w  = (const float*)d_in[2];
    float* out = (float*)d_out;

    char* p = (char*)d_ws;
    double* d_norm = (double*)p;                          p += 16;
    unsigned long long* key64   = (unsigned long long*)p; p += (size_t)N_NODES * 8;
    unsigned long long* slotKey = (unsigned long long*)p; p += (size_t)N_NODES * 8;
    float* mappingF = (float*)p; p += (size_t)N_NODES * 4;
    int*   slotIdx  = (int*)p;   p += (size_t)N_NODES * 4;
    int*   perm     = (int*)p;   p += (size_t)K_SEL * 4;
    float* selDot   = (float*)p; p += (size_t)K_SEL * 4;
    int*   hist     = (int*)p;   p += (size_t)NBUCKET * 4;
    int*   counter  = (int*)p;   p += 16;                 /* adjacent to hist */
    int*   start    = (int*)p;   p += (size_t)NBUCKET * 4;
    int*   chunkSums= (int*)p;   p += (size_t)NCHUNK * 4;
    int*   chunkOff = (int*)p;   p += (size_t)NCHUNK * 4;

    /* zero hist + scan counter in one async fill (graph-capture safe) */
    hipMemsetAsync(hist, 0, (size_t)NBUCKET * 4 + 16, stream);

    int score_blocks = (N_NODES + 63) / 64;
    score_kernel<<<score_blocks, 64, 0, stream>>>(x, w, key64, hist);

    scan_kernel<<<NCHUNK, 256, 0, stream>>>(hist, w, d_norm, start, chunkSums,
                                            chunkOff, counter);

    int node_blocks = (N_NODES + 255) / 256;
    scatter_kernel<<<node_blocks, 256, 0, stream>>>(key64, start, chunkOff,
                                                    slotKey, slotIdx);

    rank_kernel<<<node_blocks, 256, 0, stream>>>(slotKey, slotIdx, start, hist,
                                                 chunkOff, mappingF, perm, selDot);

    out_kernel<<<GATHER_BLOCKS + EDGE_BLOCKS, 256, 0, stream>>>(x, perm, selDot, d_norm,
                                                                ei, mappingF, out);
}

// Round 6
// 335.993 us; speedup vs baseline: 1.0014x; 1.0014x over previous
//
#include <hip/hip_runtime.h>
#include <math.h>

#define N_NODES 100000
#define N_FEAT  256
#define K_SEL   50000
#define N_EDGES 3200000
#define NBUCKET 65536
#define NCHUNK  256                         /* NBUCKET / 256 bins per chunk */

#define GATHER_BLOCKS (K_SEL / 4)           /* 4 rows (64 lanes ea) per 256-thr block */
#define EDGE_BLOCKS   (N_EDGES / (4 * 256)) /* 4 edges per thread */

typedef float __attribute__((ext_vector_type(4))) floatx4;
typedef int   __attribute__((ext_vector_type(4))) intx4;

// ---- key encodings -------------------------------------------------------
// ascending uint64 key == descending z, so stable-ascending == top_k order
__device__ __forceinline__ unsigned long long descKey(double z) {
    unsigned long long u = (unsigned long long)__double_as_longlong(z);
    unsigned long long a = (u >> 63) ? ~u : (u | 0x8000000000000000ULL);
    return ~a;
}

// exact inverse of descKey (bit-exact roundtrip, finite values)
__device__ __forceinline__ double invKey(unsigned long long k) {
    unsigned long long a = ~k;
    unsigned long long u = (a >> 63) ? (a & 0x7FFFFFFFFFFFFFFFULL) : ~a;
    return __longlong_as_double((long long)u);
}

__device__ __forceinline__ unsigned int bucketOfFloat(float zf) {
    unsigned int u = __float_as_uint(zf);
    unsigned int a = (u >> 31) ? ~u : (u | 0x80000000u);
    return (~a) >> 16;
}

// ---- kernels -------------------------------------------------------------
// score: EXACT R1 form (fastest measured: <59us vs 83-85us for all
// "improved" layouts). One wave per row: the x-read is one fully-coalesced
// 1KB load instruction (64 lanes x 16B contiguous). Empirical law from
// R1/R3/R4/R5: per-instruction contiguity of this read is what sets score's
// time; fragmenting it (4x256B or 64 scattered lines) costs +28us.
// fp64 accumulate; ranking is monotone in raw dot -> no norm/tanh here.
__global__ void score_kernel(const float* __restrict__ x, const float* __restrict__ w,
                             unsigned long long* __restrict__ key64,
                             int* __restrict__ hist) {
    int row  = (int)((blockIdx.x * blockDim.x + threadIdx.x) >> 6);
    int lane = threadIdx.x & 63;
    if (row >= N_NODES) return;
    const float4 xv = ((const float4*)(x + (size_t)row * N_FEAT))[lane];
    const float4 wv = ((const float4*)w)[lane];
    double acc = (double)xv.x * (double)wv.x + (double)xv.y * (double)wv.y +
                 (double)xv.z * (double)wv.z + (double)xv.w * (double)wv.w;
    for (int m = 32; m >= 1; m >>= 1) acc += __shfl_xor(acc, m, 64);
    if (lane == 0) {
        key64[row] = descKey(acc);
        atomicAdd(&hist[bucketOfFloat((float)acc)], 1);
    }
}

// chunked scan: block c scans its 256 bins into chunk-LOCAL exclusive
// prefixes (-> start[]); last-arriving block scans the 256 chunk totals into
// chunkOff[]. Block 0 additionally computes ||w|| in fp64.
__global__ void __launch_bounds__(256) scan_kernel(const int* __restrict__ hist,
                                                   const float* __restrict__ w,
                                                   double* __restrict__ normp,
                                                   int* __restrict__ start,
                                                   int* __restrict__ chunkSums,
                                                   int* __restrict__ chunkOff,
                                                   int* __restrict__ counter) {
    __shared__ int s[256];
    __shared__ double sd[256];
    __shared__ int lastFlag;
    int c = blockIdx.x, t = threadIdx.x;
    if (c == 0) {                       /* ||w|| reduction, fp64 */
        double v = (double)w[t];
        sd[t] = v * v;
        __syncthreads();
        for (int off = 128; off > 0; off >>= 1) {
            if (t < off) sd[t] += sd[t + off];
            __syncthreads();
        }
        if (t == 0) normp[0] = sqrt(sd[0]);
    }
    int v = hist[c * 256 + t];
    s[t] = v;
    __syncthreads();
    for (int off = 1; off < 256; off <<= 1) {
        int add = (t >= off) ? s[t - off] : 0;
        __syncthreads();
        s[t] += add;
        __syncthreads();
    }
    start[c * 256 + t] = s[t] - v; /* chunk-local exclusive prefix */
    if (t == 0) {
        atomicExch(&chunkSums[c], s[255]);   /* device-scope publish */
        __threadfence();
        int old = atomicAdd(counter, 1);
        lastFlag = (old == NCHUNK - 1);
    }
    __syncthreads();
    if (!lastFlag) return;
    int wsum = atomicAdd(&chunkSums[t], 0);  /* device-coherent read */
    __syncthreads();
    s[t] = wsum;
    __syncthreads();
    for (int off = 1; off < 256; off <<= 1) {
        int add = (t >= off) ? s[t - off] : 0;
        __syncthreads();
        s[t] += add;
        __syncthreads();
    }
    chunkOff[t] = s[t] - wsum; /* global exclusive offset of chunk t */
}

// scatter nodes to their bucket's slot range; consumes start[] via atomicAdd
__global__ void scatter_kernel(const unsigned long long* __restrict__ key64,
                               int* __restrict__ start,
                               const int* __restrict__ chunkOff,
                               unsigned long long* __restrict__ slotKey,
                               int* __restrict__ slotIdx) {
    int i = blockIdx.x * blockDim.x + threadIdx.x;
    if (i >= N_NODES) return;
    unsigned long long k = key64[i];
    int b = (int)bucketOfFloat((float)invKey(k));
    int pos = atomicAdd(&start[b], 1) + chunkOff[b >> 8];
    slotKey[pos] = k;
    slotIdx[pos] = i;
}

// exact rank within bucket via fp64 key + index tie-break.
// post-scatter start[b]+chunkOff == bucket end; begin = end - hist[b].
// buckets entirely below the cutoff (st >= K) short-circuit to mapping=-1.
__global__ void rank_kernel(const unsigned long long* __restrict__ slotKey,
                            const int* __restrict__ slotIdx,
                            const int* __restrict__ start, const int* __restrict__ hist,
                            const int* __restrict__ chunkOff,
                            float* __restrict__ mappingF, int* __restrict__ perm,
                            float* __restrict__ selDot) {
    int s = blockIdx.x * blockDim.x + threadIdx.x;
    if (s >= N_NODES) return;
    unsigned long long myKey = slotKey[s];
    int i = slotIdx[s];
    float df = (float)invKey(myKey);
    int b = (int)bucketOfFloat(df);
    int end = start[b] + chunkOff[b >> 8];
    int cnt = hist[b];
    int st = end - cnt;
    if (st >= K_SEL) {                        /* whole bucket below cutoff */
        mappingF[i] = -1.0f;
        return;
    }
    int rank = 0;
    if (cnt > 1) {
        for (int q = st; q < end; ++q) {
            unsigned long long k = slotKey[q];
            if (k < myKey || (k == myKey && slotIdx[q] < i)) ++rank;
        }
    }
    int p = st + rank;
    if (p < K_SEL) {
        mappingF[i] = (float)p;
        perm[p] = i;
        selDot[p] = df;
    } else {
        mappingF[i] = -1.0f;
    }
}

// fused output: blocks [0,GATHER_BLOCKS) gather+gate x rows (tanh here, fp32,
// selected rows only); blocks [GATHER_BLOCKS,...) remap edges, 4/thread int4
__global__ void out_kernel(const float* __restrict__ x, const int* __restrict__ perm,
                           const float* __restrict__ selDot,
                           const double* __restrict__ normp,
                           const int* __restrict__ ei,
                           const float* __restrict__ mappingF,
                           float* __restrict__ out) {
    if (blockIdx.x < GATHER_BLOCKS) {
        int tid = blockIdx.x * 256 + threadIdx.x;
        int r = tid >> 6;
        int c = (tid & 63) << 2;
        int src = perm[r];
        float sc = tanhf(selDot[r] / (float)normp[0]);
        float4 v = *(const float4*)(x + (size_t)src * N_FEAT + c);
        floatx4 o;
        o.x = v.x * sc; o.y = v.y * sc; o.z = v.z * sc; o.w = v.w * sc;
        __builtin_nontemporal_store(o, (floatx4*)(out + (size_t)r * N_FEAT + c));
    } else {
        int tid = (blockIdx.x - GATHER_BLOCKS) * 256 + threadIdx.x;
        int e = tid << 2;
        intx4 a = __builtin_nontemporal_load((const intx4*)(ei + e));
        intx4 b = __builtin_nontemporal_load((const intx4*)(ei + N_EDGES + e));
        float* oeu = out + (size_t)K_SEL * N_FEAT;
        float* oev = oeu + N_EDGES;
        float m0 = mappingF[a.x], m1 = mappingF[a.y];
        float m2 = mappingF[a.z], m3 = mappingF[a.w];
        float n0 = mappingF[b.x], n1 = mappingF[b.y];
        float n2 = mappingF[b.z], n3 = mappingF[b.w];
        floatx4 ou, ov;
        bool v0 = (m0 >= 0.0f) && (n0 >= 0.0f);
        bool v1 = (m1 >= 0.0f) && (n1 >= 0.0f);
        bool v2 = (m2 >= 0.0f) && (n2 >= 0.0f);
        bool v3 = (m3 >= 0.0f) && (n3 >= 0.0f);
        ou.x = v0 ? m0 : -1.0f; ov.x = v0 ? n0 : -1.0f;
        ou.y = v1 ? m1 : -1.0f; ov.y = v1 ? n1 : -1.0f;
        ou.z = v2 ? m2 : -1.0f; ov.z = v2 ? n2 : -1.0f;
        ou.w = v3 ? m3 : -1.0f; ov.w = v3 ? n3 : -1.0f;
        __builtin_nontemporal_store(ou, (floatx4*)(oeu + e));
        __builtin_nontemporal_store(ov, (floatx4*)(oev + e));
    }
}

// ---- launch --------------------------------------------------------------
extern "C" void kernel_launch(void* const* d_in, const int* in_sizes, int n_in,
                              void* d_out, int out_size, void* d_ws, size_t ws_size,
                              hipStream_t stream) {
    const float* x  = (const float*)d_in[0];
    const int*   ei = (const int*)d_in[1];
    const float* w  = (const float*)d_in[2];
    float* out = (float*)d_out;

    char* p = (char*)d_ws;
    double* d_norm = (double*)p;                          p += 16;
    unsigned long long* key64   = (unsigned long long*)p; p += (size_t)N_NODES * 8;
    unsigned long long* slotKey = (unsigned long long*)p; p += (size_t)N_NODES * 8;
    float* mappingF = (float*)p; p += (size_t)N_NODES * 4;
    int*   slotIdx  = (int*)p;   p += (size_t)N_NODES * 4;
    int*   perm     = (int*)p;   p += (size_t)K_SEL * 4;
    float* selDot   = (float*)p; p += (size_t)K_SEL * 4;
    int*   hist     = (int*)p;   p += (size_t)NBUCKET * 4;
    int*   counter  = (int*)p;   p += 16;                 /* adjacent to hist */
    int*   start    = (int*)p;   p += (size_t)NBUCKET * 4;
    int*   chunkSums= (int*)p;   p += (size_t)NCHUNK * 4;
    int*   chunkOff = (int*)p;   p += (size_t)NCHUNK * 4;

    /* zero hist + scan counter in one async fill (graph-capture safe) */
    hipMemsetAsync(hist, 0, (size_t)NBUCKET * 4 + 16, stream);

    int waves_blocks = (N_NODES * 64 + 255) / 256;
    score_kernel<<<waves_blocks, 256, 0, stream>>>(x, w, key64, hist);

    scan_kernel<<<NCHUNK, 256, 0, stream>>>(hist, w, d_norm, start, chunkSums,
                                            chunkOff, counter);

    int node_blocks = (N_NODES + 255) / 256;
    scatter_kernel<<<node_blocks, 256, 0, stream>>>(key64, start, chunkOff,
                                                    slotKey, slotIdx);

    rank_kernel<<<node_blocks, 256, 0, stream>>>(slotKey, slotIdx, start, hist,
                                                 chunkOff, mappingF, perm, selDot);

    out_kernel<<<GATHER_BLOCKS + EDGE_BLOCKS, 256, 0, stream>>>(x, perm, selDot, d_norm,
                                                                ei, mappingF, out);
}